// Round 1
// baseline (10479.261 us; speedup 1.0000x reference)
//
#include <hip/hip_runtime.h>
#include <cmath>

#define Bn   128
#define Cn   8
#define Fn   58
#define Tn   249
#define RCn  24
#define FT   14442      // Fn*Tn
#define CFT  115536     // Cn*Fn*Tn
#define OUTB 346608     // 3*CFT per-batch output
#define IH   60
#define IW   251

// ---------------------------------------------------------------------------
// differ = concat([x[...,:1], W_diff@x + b_diff (shift) - x[...,:-1]], -1)
// Q = wq@differ + bq ; K = wk@differ + bk ; V = differ
// thread per (b, f, t)
// ---------------------------------------------------------------------------
__global__ void k_differ_qk(const float* __restrict__ x,
                            const float* __restrict__ w_diff, const float* __restrict__ b_diff,
                            const float* __restrict__ wq, const float* __restrict__ bq,
                            const float* __restrict__ wk, const float* __restrict__ bk,
                            float* __restrict__ V, float* __restrict__ Q, float* __restrict__ K) {
    int gid = blockIdx.x * blockDim.x + threadIdx.x;
    if (gid >= Bn * FT) return;
    int b  = gid / FT;
    int ft = gid % FT;
    int t  = ft % Tn;
    const float* xb = x + (size_t)b * CFT + ft;

    float xv[Cn], d[Cn];
    #pragma unroll
    for (int c = 0; c < Cn; c++) xv[c] = xb[c * FT];

    if (t == 0) {
        #pragma unroll
        for (int c = 0; c < Cn; c++) d[c] = xv[c];
    } else {
        #pragma unroll
        for (int o = 0; o < Cn; o++) {
            float s = b_diff[o];
            #pragma unroll
            for (int c = 0; c < Cn; c++) s += w_diff[o * Cn + c] * xv[c];
            d[o] = s - xb[o * FT - 1];
        }
    }

    float* Vb = V + (size_t)b * CFT + ft;
    float* Qb = Q + (size_t)b * CFT + ft;
    float* Kb = K + (size_t)b * CFT + ft;
    #pragma unroll
    for (int o = 0; o < Cn; o++) {
        Vb[o * FT] = d[o];
        float q = bq[o], k = bk[o];
        #pragma unroll
        for (int c = 0; c < Cn; c++) { q += wq[o * Cn + c] * d[c]; k += wk[o * Cn + c] * d[c]; }
        Qb[o * FT] = q;
        Kb[o * FT] = k;
    }
}

// ---------------------------------------------------------------------------
// Y[b,o,l] = sum_i W[o,i] * X[b,i,l] + bias[o]   (pointwise conv == matmul on rows)
// block: 256 threads over l; 8 outputs o per thread (register blocking)
// ---------------------------------------------------------------------------
__global__ void k_wmat(const float* __restrict__ X, const float* __restrict__ W,
                       const float* __restrict__ bias, float* __restrict__ Y,
                       int n_out, int n_in, int d, int sX, int sY) {
    int l  = blockIdx.x * 256 + threadIdx.x;
    int og = blockIdx.y * 8;
    int b  = blockIdx.z;
    if (l >= d) return;
    const float* Xb = X + (size_t)b * sX + l;
    int jmax = min(8, n_out - og);
    float acc[8];
    for (int j = 0; j < 8; j++) acc[j] = (j < jmax) ? bias[og + j] : 0.f;

    if (jmax == 8) {
        for (int i = 0; i < n_in; i++) {
            float xv = Xb[(size_t)i * d];
            #pragma unroll
            for (int j = 0; j < 8; j++) acc[j] += W[(og + j) * n_in + i] * xv;
        }
    } else {
        for (int i = 0; i < n_in; i++) {
            float xv = Xb[(size_t)i * d];
            for (int j = 0; j < jmax; j++) acc[j] += W[(og + j) * n_in + i] * xv;
        }
    }
    float* Yb = Y + (size_t)b * sY + l;
    for (int j = 0; j < jmax; j++) Yb[(size_t)(og + j) * d] = acc[j];
}

// ---------------------------------------------------------------------------
// kernel-size-2 stride-2 variant: Y[b,o,j] = sum_i W[o,i,0]X[b,i,2j]+W[o,i,1]X[b,i,2j+1]+bias[o]
// ---------------------------------------------------------------------------
__global__ void k_conv2s2(const float* __restrict__ X, const float* __restrict__ W,
                          const float* __restrict__ bias, float* __restrict__ Y,
                          int n_out, int n_in, int d_in, int d_out, int sX, int sY) {
    int j  = blockIdx.x * 256 + threadIdx.x;
    int og = blockIdx.y * 8;
    int b  = blockIdx.z;
    if (j >= d_out) return;
    const float* Xb = X + (size_t)b * sX + 2 * j;
    int jmax = min(8, n_out - og);
    float acc[8];
    for (int jj = 0; jj < 8; jj++) acc[jj] = (jj < jmax) ? bias[og + jj] : 0.f;
    for (int i = 0; i < n_in; i++) {
        float x0 = Xb[(size_t)i * d_in];
        float x1 = Xb[(size_t)i * d_in + 1];
        for (int jj = 0; jj < jmax; jj++) {
            const float* w = W + ((size_t)(og + jj) * n_in + i) * 2;
            acc[jj] += w[0] * x0 + w[1] * x1;
        }
    }
    float* Yb = Y + (size_t)b * sY + j;
    for (int jj = 0; jj < jmax; jj++) Yb[(size_t)(og + jj) * d_out] = acc[jj];
}

// ---------------------------------------------------------------------------
// S[b,r,c] = scale * sum_l Q[b,r,l]*K[b,c,l]   — 32x32 LDS-tiled
// ---------------------------------------------------------------------------
__global__ void k_scores(const float* __restrict__ Q, const float* __restrict__ K,
                         float* __restrict__ S, int n, int d, int sQ, float scale) {
    __shared__ float Qs[32][33];
    __shared__ float Ks[32][33];
    int b  = blockIdx.z;
    int r0 = blockIdx.x * 32, c0 = blockIdx.y * 32;
    int tx = threadIdx.x & 15, ty = threadIdx.x >> 4;
    const float* Qb = Q + (size_t)b * sQ;
    const float* Kb = K + (size_t)b * sQ;
    float acc00 = 0.f, acc01 = 0.f, acc10 = 0.f, acc11 = 0.f;

    for (int kk = 0; kk < d; kk += 32) {
        #pragma unroll
        for (int e = 0; e < 4; e++) {
            int li = threadIdx.x + e * 256;
            int rr = li >> 5, cc = li & 31;
            int gc = kk + cc;
            int gr = r0 + rr;
            Qs[rr][cc] = (gr < n && gc < d) ? Qb[(size_t)gr * d + gc] : 0.f;
            int gr2 = c0 + rr;
            Ks[rr][cc] = (gr2 < n && gc < d) ? Kb[(size_t)gr2 * d + gc] : 0.f;
        }
        __syncthreads();
        #pragma unroll
        for (int k = 0; k < 32; k++) {
            float q0 = Qs[ty * 2][k],     q1 = Qs[ty * 2 + 1][k];
            float k0 = Ks[tx * 2][k],     k1 = Ks[tx * 2 + 1][k];
            acc00 += q0 * k0; acc01 += q0 * k1;
            acc10 += q1 * k0; acc11 += q1 * k1;
        }
        __syncthreads();
    }
    int r = r0 + ty * 2, c = c0 + tx * 2;
    float* Sb = S + (size_t)b * n * n;
    if (r < n     && c < n)     Sb[(size_t)r * n + c]           = acc00 * scale;
    if (r < n     && c + 1 < n) Sb[(size_t)r * n + c + 1]       = acc01 * scale;
    if (r + 1 < n && c < n)     Sb[(size_t)(r + 1) * n + c]     = acc10 * scale;
    if (r + 1 < n && c + 1 < n) Sb[(size_t)(r + 1) * n + c + 1] = acc11 * scale;
}

// ---------------------------------------------------------------------------
// column softmax in-place (softmax over axis=1, i.e. rows, per column m)
// one block per batch; thread m handles one column
// ---------------------------------------------------------------------------
__global__ void k_softmax(float* __restrict__ S, int n) {
    int b = blockIdx.x;
    int m = threadIdx.x;
    if (m >= n) return;
    float* Sb = S + (size_t)b * n * n;
    float mx = -1e30f;
    for (int r = 0; r < n; r++) mx = fmaxf(mx, Sb[(size_t)r * n + m]);
    float sum = 0.f;
    for (int r = 0; r < n; r++) {
        float e = expf(Sb[(size_t)r * n + m] - mx);
        Sb[(size_t)r * n + m] = e;
        sum += e;
    }
    float inv = 1.f / sum;
    for (int r = 0; r < n; r++) Sb[(size_t)r * n + m] *= inv;
}

// ---------------------------------------------------------------------------
// out[b,sec,n,l] (+)= sum_m alpha[b,n,m] * V[b,m,l]
// ---------------------------------------------------------------------------
__global__ void k_apply(const float* __restrict__ A, const float* __restrict__ V,
                        float* __restrict__ out, int n, int dv, int sec, int add) {
    int l  = blockIdx.x * 256 + threadIdx.x;
    int ng = blockIdx.y * 8;
    int b  = blockIdx.z;
    if (l >= dv) return;
    const float* Vb = V + (size_t)b * CFT + l;
    const float* Ab = A + (size_t)b * n * n;
    int jmax = min(8, n - ng);
    float acc[8] = {0.f, 0.f, 0.f, 0.f, 0.f, 0.f, 0.f, 0.f};

    if (jmax == 8) {
        for (int m = 0; m < n; m++) {
            float vv = Vb[(size_t)m * dv];
            #pragma unroll
            for (int j = 0; j < 8; j++) acc[j] += Ab[(size_t)(ng + j) * n + m] * vv;
        }
    } else {
        for (int m = 0; m < n; m++) {
            float vv = Vb[(size_t)m * dv];
            for (int j = 0; j < jmax; j++) acc[j] += Ab[(size_t)(ng + j) * n + m] * vv;
        }
    }
    float* ob = out + (size_t)b * OUTB + (size_t)sec * CFT + l;
    for (int j = 0; j < jmax; j++) {
        size_t oi = (size_t)(ng + j) * dv;
        ob[oi] = add ? (ob[oi] + acc[j]) : acc[j];
    }
}

// ---------------------------------------------------------------------------
// xr spatial mean per (b, rc): mean over F,T of BN(conv3x3(inp)+b_res)
// ---------------------------------------------------------------------------
__global__ void k_mean(const float* __restrict__ inp, const float* __restrict__ w_res,
                       const float* __restrict__ b_res, const float* __restrict__ bn_gamma,
                       const float* __restrict__ bn_beta, const float* __restrict__ bn_mean,
                       const float* __restrict__ bn_var, float* __restrict__ meanbuf) {
    int b  = blockIdx.x / RCn;
    int rc = blockIdx.x % RCn;
    float w[9];
    #pragma unroll
    for (int i = 0; i < 9; i++) w[i] = w_res[rc * 9 + i];
    float g    = bn_gamma[rc] * rsqrtf(bn_var[rc] + 1e-5f);
    float bias = (b_res[rc] - bn_mean[rc]) * g + bn_beta[rc];
    const float* ib = inp + (size_t)b * IH * IW;

    float sum = 0.f;
    for (int idx = threadIdx.x; idx < FT; idx += 256) {
        int f = idx / Tn, t = idx % Tn;
        const float* p = ib + f * IW + t;
        float v = w[0]*p[0]     + w[1]*p[1]     + w[2]*p[2]
                + w[3]*p[IW]    + w[4]*p[IW+1]  + w[5]*p[IW+2]
                + w[6]*p[2*IW]  + w[7]*p[2*IW+1]+ w[8]*p[2*IW+2];
        sum += v * g + bias;
    }
    __shared__ float red[256];
    red[threadIdx.x] = sum;
    __syncthreads();
    for (int s = 128; s > 0; s >>= 1) {
        if (threadIdx.x < s) red[threadIdx.x] += red[threadIdx.x + s];
        __syncthreads();
    }
    if (threadIdx.x == 0) meanbuf[b * RCn + rc] = red[0] / (float)FT;
}

// ---------------------------------------------------------------------------
// dyReLU coefficient MLP per batch: theta(24) -> h(6) relu -> 96 sigmoid coefs
// ---------------------------------------------------------------------------
__global__ void k_coef(const float* __restrict__ meanbuf, const float* __restrict__ w1,
                       const float* __restrict__ b1, const float* __restrict__ w2,
                       const float* __restrict__ b2, float* __restrict__ coef) {
    int b = blockIdx.x;
    int k = threadIdx.x;
    if (k >= 4 * RCn) return;
    const float* th = meanbuf + b * RCn;
    float h[6];
    #pragma unroll
    for (int j = 0; j < 6; j++) {
        float s = b1[j];
        #pragma unroll
        for (int c = 0; c < RCn; c++) s += th[c] * w1[j * RCn + c];
        h[j] = fmaxf(s, 0.f);
    }
    float s = b2[k];
    #pragma unroll
    for (int j = 0; j < 6; j++) s += h[j] * w2[k * 6 + j];
    float g2 = 2.f / (1.f + expf(-s)) - 1.f;
    const float lam[4] = {1.f, 1.f, 0.5f, 0.5f};
    const float ini[4] = {1.f, 0.f, 0.f, 0.f};
    coef[b * 96 + k] = g2 * lam[k & 3] + ini[k & 3];
}

// ---------------------------------------------------------------------------
// recompute conv+BN, apply dyReLU, out += xr  (thread per output element)
// ---------------------------------------------------------------------------
__global__ void k_xr_add(const float* __restrict__ inp, const float* __restrict__ w_res,
                         const float* __restrict__ b_res, const float* __restrict__ bn_gamma,
                         const float* __restrict__ bn_beta, const float* __restrict__ bn_mean,
                         const float* __restrict__ bn_var, const float* __restrict__ coef,
                         float* __restrict__ out) {
    int gid = blockIdx.x * blockDim.x + threadIdx.x;
    if (gid >= Bn * RCn * FT) return;
    int t   = gid % Tn;
    int tmp = gid / Tn;
    int f   = tmp % Fn;  tmp /= Fn;
    int rc  = tmp % RCn;
    int b   = tmp / RCn;

    const float* wp = w_res + rc * 9;
    float g    = bn_gamma[rc] * rsqrtf(bn_var[rc] + 1e-5f);
    float bias = (b_res[rc] - bn_mean[rc]) * g + bn_beta[rc];
    const float* p = inp + (size_t)b * IH * IW + f * IW + t;
    float v = wp[0]*p[0]    + wp[1]*p[1]      + wp[2]*p[2]
            + wp[3]*p[IW]   + wp[4]*p[IW+1]   + wp[5]*p[IW+2]
            + wp[6]*p[2*IW] + wp[7]*p[2*IW+1] + wp[8]*p[2*IW+2];
    float xv = v * g + bias;

    const float* cf = coef + ((size_t)b * RCn + rc) * 4;
    float r = fmaxf(xv * cf[0] + cf[2], xv * cf[1] + cf[3]);
    out[gid] += r;
}

// ---------------------------------------------------------------------------
extern "C" void kernel_launch(void* const* d_in, const int* in_sizes, int n_in,
                              void* d_out, int out_size, void* d_ws, size_t ws_size,
                              hipStream_t stream) {
    const float* x        = (const float*)d_in[0];
    const float* inp      = (const float*)d_in[1];
    const float* w_diff   = (const float*)d_in[2];
    const float* b_diff   = (const float*)d_in[3];
    const float* w_res    = (const float*)d_in[4];
    const float* b_res    = (const float*)d_in[5];
    const float* bn_gamma = (const float*)d_in[6];
    const float* bn_beta  = (const float*)d_in[7];
    const float* bn_mean  = (const float*)d_in[8];
    const float* bn_var   = (const float*)d_in[9];
    const float* dy_w1    = (const float*)d_in[10];
    const float* dy_b1    = (const float*)d_in[11];
    const float* dy_w2    = (const float*)d_in[12];
    const float* dy_b2    = (const float*)d_in[13];
    const float* wq       = (const float*)d_in[14];
    const float* bq       = (const float*)d_in[15];
    const float* wk       = (const float*)d_in[16];
    const float* bk       = (const float*)d_in[17];
    const float* fq0_w    = (const float*)d_in[18];
    const float* fq0_b    = (const float*)d_in[19];
    const float* fk0_w    = (const float*)d_in[20];
    const float* fk0_b    = (const float*)d_in[21];
    const float* cq0_w    = (const float*)d_in[22];
    const float* cq0_b    = (const float*)d_in[23];
    const float* ck0_w    = (const float*)d_in[24];
    const float* ck0_b    = (const float*)d_in[25];
    const float* tq0_w    = (const float*)d_in[26];
    const float* tq0_b    = (const float*)d_in[27];
    const float* tk0_w    = (const float*)d_in[28];
    const float* tk0_b    = (const float*)d_in[29];
    const float* tq1_w    = (const float*)d_in[30];
    const float* tq1_b    = (const float*)d_in[31];
    const float* tk1_w    = (const float*)d_in[32];
    const float* tk1_b    = (const float*)d_in[33];

    float* out = (float*)d_out;
    float* ws  = (float*)d_ws;

    const size_t NB = (size_t)Bn * CFT;
    float* V       = ws;
    float* Q       = ws + NB;
    float* K       = ws + 2 * NB;
    float* Qp      = ws + 3 * NB;
    float* Kp      = ws + 4 * NB;
    float* S       = ws + 5 * NB;
    float* meanbuf = ws + 5 * NB + (size_t)Bn * Tn * Tn;
    float* coef    = meanbuf + Bn * RCn;

    // 1. differ / Q / K
    {
        int total = Bn * FT;
        k_differ_qk<<<dim3((total + 255) / 256), dim3(256), 0, stream>>>(
            x, w_diff, b_diff, wq, bq, wk, bk, V, Q, K);
    }

    auto attend = [&](const float* Qv, const float* Kv, int n, int dq, int sQ,
                      int dv, int sec, int add) {
        float scale = 1.0f / sqrtf((float)dq);
        dim3 g1((n + 31) / 32, (n + 31) / 32, Bn);
        k_scores<<<g1, dim3(256), 0, stream>>>(Qv, Kv, S, n, dq, sQ, scale);
        k_softmax<<<dim3(Bn), dim3(256), 0, stream>>>(S, n);
        dim3 g2((dv + 255) / 256, (n + 7) / 8, Bn);
        k_apply<<<g2, dim3(256), 0, stream>>>(S, V, out, n, dv, sec, add);
    };

    // ---- f branch: n=58, d=1992, sec=0
    attend(Q, K, Fn, 1992, CFT, 1992, 0, 0);
    {
        dim3 g((1992 + 255) / 256, (Fn + 7) / 8, Bn);
        k_wmat<<<g, dim3(256), 0, stream>>>(Q, fq0_w, fq0_b, Qp, Fn, Fn, 1992, CFT, CFT);
        k_wmat<<<g, dim3(256), 0, stream>>>(K, fk0_w, fk0_b, Kp, Fn, Fn, 1992, CFT, CFT);
    }
    attend(Qp, Kp, Fn, 1992, CFT, 1992, 0, 1);

    // ---- c branch: n=8, d=14442, sec=1
    attend(Q, K, Cn, FT, CFT, FT, 1, 0);
    {
        dim3 g((FT + 255) / 256, 1, Bn);
        k_wmat<<<g, dim3(256), 0, stream>>>(Q, cq0_w, cq0_b, Qp, Cn, Cn, FT, CFT, CFT);
        k_wmat<<<g, dim3(256), 0, stream>>>(K, ck0_w, ck0_b, Kp, Cn, Cn, FT, CFT, CFT);
    }
    attend(Qp, Kp, Cn, FT, CFT, FT, 1, 1);

    // ---- t branch: n=249, dv=464, sec=2
    attend(Q, K, Tn, 464, CFT, 464, 2, 0);
    {
        dim3 g((464 + 255) / 256, (Tn + 7) / 8, Bn);
        k_wmat<<<g, dim3(256), 0, stream>>>(Q, tq0_w, tq0_b, Qp, Tn, Tn, 464, CFT, CFT);
        k_wmat<<<g, dim3(256), 0, stream>>>(K, tk0_w, tk0_b, Kp, Tn, Tn, 464, CFT, CFT);
    }
    attend(Qp, Kp, Tn, 464, CFT, 464, 2, 1);
    {
        dim3 g(1, (Tn + 7) / 8, Bn);
        k_conv2s2<<<g, dim3(256), 0, stream>>>(Q, tq1_w, tq1_b, Qp, Tn, Tn, 464, 232, CFT, Tn * 232);
        k_conv2s2<<<g, dim3(256), 0, stream>>>(K, tk1_w, tk1_b, Kp, Tn, Tn, 464, 232, CFT, Tn * 232);
    }
    attend(Qp, Kp, Tn, 232, Tn * 232, 464, 2, 1);

    // ---- xr residual path
    k_mean<<<dim3(Bn * RCn), dim3(256), 0, stream>>>(
        inp, w_res, b_res, bn_gamma, bn_beta, bn_mean, bn_var, meanbuf);
    k_coef<<<dim3(Bn), dim3(128), 0, stream>>>(meanbuf, dy_w1, dy_b1, dy_w2, dy_b2, coef);
    {
        int total = Bn * RCn * FT;
        k_xr_add<<<dim3((total + 255) / 256), dim3(256), 0, stream>>>(
            inp, w_res, b_res, bn_gamma, bn_beta, bn_mean, bn_var, coef, out);
    }
}

// Round 2
// 6192.953 us; speedup vs baseline: 1.6921x; 1.6921x over previous
//
#include <hip/hip_runtime.h>
#include <cmath>

#define Bn   128
#define Cn   8
#define Fn   58
#define Tn   249
#define RCn  24
#define FT   14442      // Fn*Tn
#define CFT  115536     // Cn*Fn*Tn
#define OUTB 346608     // 3*CFT per-batch output
#define IH   60
#define IW   251

// ---------------------------------------------------------------------------
// differ = concat([x[...,:1], W_diff@x + b_diff (shift) - x[...,:-1]], -1)
// Q = wq@differ + bq ; K = wk@differ + bk ; V = differ
// ---------------------------------------------------------------------------
__global__ void k_differ_qk(const float* __restrict__ x,
                            const float* __restrict__ w_diff, const float* __restrict__ b_diff,
                            const float* __restrict__ wq, const float* __restrict__ bq,
                            const float* __restrict__ wk, const float* __restrict__ bk,
                            float* __restrict__ V, float* __restrict__ Q, float* __restrict__ K) {
    int gid = blockIdx.x * blockDim.x + threadIdx.x;
    if (gid >= Bn * FT) return;
    int b  = gid / FT;
    int ft = gid % FT;
    int t  = ft % Tn;
    const float* xb = x + (size_t)b * CFT + ft;

    float xv[Cn], d[Cn];
    #pragma unroll
    for (int c = 0; c < Cn; c++) xv[c] = xb[c * FT];

    if (t == 0) {
        #pragma unroll
        for (int c = 0; c < Cn; c++) d[c] = xv[c];
    } else {
        #pragma unroll
        for (int o = 0; o < Cn; o++) {
            float s = b_diff[o];
            #pragma unroll
            for (int c = 0; c < Cn; c++) s += w_diff[o * Cn + c] * xv[c];
            d[o] = s - xb[o * FT - 1];
        }
    }

    float* Vb = V + (size_t)b * CFT + ft;
    float* Qb = Q + (size_t)b * CFT + ft;
    float* Kb = K + (size_t)b * CFT + ft;
    #pragma unroll
    for (int o = 0; o < Cn; o++) {
        Vb[o * FT] = d[o];
        float q = bq[o], k = bk[o];
        #pragma unroll
        for (int c = 0; c < Cn; c++) { q += wq[o * Cn + c] * d[c]; k += wk[o * Cn + c] * d[c]; }
        Qb[o * FT] = q;
        Kb[o * FT] = k;
    }
}

// ---------------------------------------------------------------------------
// Y[b,o,l] = sum_i W[o,i] * X[b,i,l] + bias[o]
// Fully-unrolled 8-wide output tile; clamped weight rows; guarded stores.
// (Round-1 lesson: runtime-bounded tail loops spilled acc[] to scratch.)
// ---------------------------------------------------------------------------
__global__ void k_wmat(const float* __restrict__ X, const float* __restrict__ W,
                       const float* __restrict__ bias, float* __restrict__ Y,
                       int n_out, int n_in, int d, int sX, int sY) {
    int l  = blockIdx.x * 256 + threadIdx.x;
    int og = blockIdx.y * 8;
    int b  = blockIdx.z;
    if (l >= d) return;
    const float* Xb = X + (size_t)b * sX + l;
    const float* Wr[8];
    float acc[8];
    #pragma unroll
    for (int j = 0; j < 8; j++) {
        int o = min(og + j, n_out - 1);
        Wr[j]  = W + (size_t)o * n_in;
        acc[j] = bias[o];
    }
    for (int i = 0; i < n_in; i++) {
        float xv = Xb[(size_t)i * d];
        #pragma unroll
        for (int j = 0; j < 8; j++) acc[j] += Wr[j][i] * xv;
    }
    float* Yb = Y + (size_t)b * sY + l;
    #pragma unroll
    for (int j = 0; j < 8; j++)
        if (og + j < n_out) Yb[(size_t)(og + j) * d] = acc[j];
}

// ---------------------------------------------------------------------------
// kernel-size-2 stride-2 conv: Y[b,o,j] = sum_i W[o,i,0]X[b,i,2j]+W[o,i,1]X[b,i,2j+1]
// ---------------------------------------------------------------------------
__global__ void k_conv2s2(const float* __restrict__ X, const float* __restrict__ W,
                          const float* __restrict__ bias, float* __restrict__ Y,
                          int n_out, int n_in, int d_in, int d_out, int sX, int sY) {
    int j  = blockIdx.x * 256 + threadIdx.x;
    int og = blockIdx.y * 8;
    int b  = blockIdx.z;
    if (j >= d_out) return;
    const float* Xb = X + (size_t)b * sX + 2 * j;
    const float* Wr[8];
    float acc[8];
    #pragma unroll
    for (int jj = 0; jj < 8; jj++) {
        int o = min(og + jj, n_out - 1);
        Wr[jj]  = W + (size_t)o * n_in * 2;
        acc[jj] = bias[o];
    }
    for (int i = 0; i < n_in; i++) {
        float x0 = Xb[(size_t)i * d_in];
        float x1 = Xb[(size_t)i * d_in + 1];
        #pragma unroll
        for (int jj = 0; jj < 8; jj++)
            acc[jj] += Wr[jj][2 * i] * x0 + Wr[jj][2 * i + 1] * x1;
    }
    float* Yb = Y + (size_t)b * sY + j;
    #pragma unroll
    for (int jj = 0; jj < 8; jj++)
        if (og + jj < n_out) Yb[(size_t)(og + jj) * d_out] = acc[jj];
}

// ---------------------------------------------------------------------------
// Scores with split-K: SP[bz,r,c] = sum_{k in chunk} Q[b,r,k]*K[b,c,k]
// 64x64 tile, 4x4 per thread, k-major LDS (16-deep, +4 pad).
// ---------------------------------------------------------------------------
__global__ void k_scores_sk(const float* __restrict__ Q, const float* __restrict__ K,
                            float* __restrict__ SP, int n, int d, int kz_n, int chunk,
                            int sQ) {
    __shared__ float Qs[16][68];
    __shared__ float Ks[16][68];
    int bz = blockIdx.z;
    int b  = bz / kz_n, kz = bz % kz_n;
    int k0 = kz * chunk, k1 = min(d, k0 + chunk);
    int r0 = blockIdx.x * 64, c0 = blockIdx.y * 64;
    int tx = threadIdx.x & 15, ty = threadIdx.x >> 4;
    int lrow = threadIdx.x >> 2;
    int lk   = (threadIdx.x & 3) * 4;
    const float* Qr = Q + (size_t)b * sQ + (size_t)min(r0 + lrow, n - 1) * d;
    const float* Kr = K + (size_t)b * sQ + (size_t)min(c0 + lrow, n - 1) * d;
    bool qok = (r0 + lrow) < n;
    bool kok = (c0 + lrow) < n;
    float acc[4][4] = {};

    for (int kk = k0; kk < k1; kk += 16) {
        #pragma unroll
        for (int u = 0; u < 4; u++) {
            int gk = kk + lk + u;
            bool gv = gk < k1;
            Qs[lk + u][lrow] = (qok && gv) ? Qr[gk] : 0.f;
            Ks[lk + u][lrow] = (kok && gv) ? Kr[gk] : 0.f;
        }
        __syncthreads();
        #pragma unroll
        for (int k = 0; k < 16; k++) {
            float aq[4], ak[4];
            #pragma unroll
            for (int u = 0; u < 4; u++) { aq[u] = Qs[k][ty * 4 + u]; ak[u] = Ks[k][tx * 4 + u]; }
            #pragma unroll
            for (int i = 0; i < 4; i++)
                #pragma unroll
                for (int j = 0; j < 4; j++) acc[i][j] += aq[i] * ak[j];
        }
        __syncthreads();
    }
    float* Sb = SP + (size_t)bz * n * n;
    #pragma unroll
    for (int i = 0; i < 4; i++) {
        int r = r0 + ty * 4 + i;
        #pragma unroll
        for (int j = 0; j < 4; j++) {
            int c = c0 + tx * 4 + j;
            if (r < n && c < n) Sb[(size_t)r * n + c] = acc[i][j];
        }
    }
}

// ---------------------------------------------------------------------------
// Combine split-K partials and apply 1/sqrt(d) scale. In-place safe for kz_n=1.
// ---------------------------------------------------------------------------
__global__ void k_scombine(const float* __restrict__ SP, float* __restrict__ S,
                           int n, int kz_n, float scale) {
    int idx = blockIdx.x * 256 + threadIdx.x;
    int nn = n * n;
    if (idx >= Bn * nn) return;
    int b = idx / nn, rc = idx % nn;
    float s = 0.f;
    for (int kz = 0; kz < kz_n; kz++) s += SP[((size_t)b * kz_n + kz) * nn + rc];
    S[(size_t)b * nn + rc] = s * scale;
}

// ---------------------------------------------------------------------------
// c-branch gram: 8x8 over d=FT, split into 8 l-chunks of partials.
// thread = (g 0..3)*(pair 0..63); scalar acc; LDS cross-group reduce.
// ---------------------------------------------------------------------------
#define C_LZ 8
__global__ void k_gram8(const float* __restrict__ Q, const float* __restrict__ K,
                        float* __restrict__ SP) {
    int b  = blockIdx.x / C_LZ;
    int lz = blockIdx.x % C_LZ;
    int g  = threadIdx.x >> 6;
    int p  = threadIdx.x & 63;
    int r  = p >> 3, c = p & 7;
    const float* Qb = Q + (size_t)b * CFT + (size_t)r * FT;
    const float* Kb = K + (size_t)b * CFT + (size_t)c * FT;
    int chunk = (FT + C_LZ - 1) / C_LZ;
    int l0 = lz * chunk, l1 = min(FT, l0 + chunk);
    float acc = 0.f;
    for (int l = l0 + g; l < l1; l += 4) acc += Qb[l] * Kb[l];
    __shared__ float red[256];
    red[threadIdx.x] = acc;
    __syncthreads();
    if (threadIdx.x < 64) {
        float s = red[p] + red[64 + p] + red[128 + p] + red[192 + p];
        SP[(size_t)blockIdx.x * 64 + p] = s;
    }
}

// ---------------------------------------------------------------------------
// column softmax in-place (axis=1): grid (Bn*mb), 64 threads, thread = column
// ---------------------------------------------------------------------------
__global__ void k_softmax(float* __restrict__ S, int n, int mb) {
    int b = blockIdx.x / mb;
    int m = (blockIdx.x % mb) * 64 + threadIdx.x;
    if (m >= n) return;
    float* Sb = S + (size_t)b * n * n;
    float mx = -1e30f;
    for (int r = 0; r < n; r++) mx = fmaxf(mx, Sb[(size_t)r * n + m]);
    float sum = 0.f;
    for (int r = 0; r < n; r++) {
        float e = __expf(Sb[(size_t)r * n + m] - mx);
        Sb[(size_t)r * n + m] = e;
        sum += e;
    }
    float inv = 1.f / sum;
    for (int r = 0; r < n; r++) Sb[(size_t)r * n + m] *= inv;
}

// ---------------------------------------------------------------------------
// out[b,sec,n,l] (+)= sum_m alpha[b,n,m] * V[b,m,l]
// ---------------------------------------------------------------------------
__global__ void k_apply(const float* __restrict__ A, const float* __restrict__ V,
                        float* __restrict__ out, int n, int dv, int sec, int add) {
    int l  = blockIdx.x * 256 + threadIdx.x;
    int ng = blockIdx.y * 8;
    int b  = blockIdx.z;
    if (l >= dv) return;
    const float* Vb = V + (size_t)b * CFT + l;
    const float* Ab = A + (size_t)b * n * n;
    const float* Ar[8];
    float acc[8] = {0.f, 0.f, 0.f, 0.f, 0.f, 0.f, 0.f, 0.f};
    #pragma unroll
    for (int j = 0; j < 8; j++) Ar[j] = Ab + (size_t)min(ng + j, n - 1) * n;

    for (int m = 0; m < n; m++) {
        float vv = Vb[(size_t)m * dv];
        #pragma unroll
        for (int j = 0; j < 8; j++) acc[j] += Ar[j][m] * vv;
    }
    float* ob = out + (size_t)b * OUTB + (size_t)sec * CFT + l;
    #pragma unroll
    for (int j = 0; j < 8; j++) {
        if (ng + j < n) {
            size_t oi = (size_t)(ng + j) * dv;
            ob[oi] = add ? (ob[oi] + acc[j]) : acc[j];
        }
    }
}

// ---------------------------------------------------------------------------
// xr spatial mean per (b, rc)
// ---------------------------------------------------------------------------
__global__ void k_mean(const float* __restrict__ inp, const float* __restrict__ w_res,
                       const float* __restrict__ b_res, const float* __restrict__ bn_gamma,
                       const float* __restrict__ bn_beta, const float* __restrict__ bn_mean,
                       const float* __restrict__ bn_var, float* __restrict__ meanbuf) {
    int b  = blockIdx.x / RCn;
    int rc = blockIdx.x % RCn;
    float w[9];
    #pragma unroll
    for (int i = 0; i < 9; i++) w[i] = w_res[rc * 9 + i];
    float g    = bn_gamma[rc] * rsqrtf(bn_var[rc] + 1e-5f);
    float bias = (b_res[rc] - bn_mean[rc]) * g + bn_beta[rc];
    const float* ib = inp + (size_t)b * IH * IW;

    float sum = 0.f;
    for (int idx = threadIdx.x; idx < FT; idx += 256) {
        int f = idx / Tn, t = idx % Tn;
        const float* p = ib + f * IW + t;
        float v = w[0]*p[0]     + w[1]*p[1]     + w[2]*p[2]
                + w[3]*p[IW]    + w[4]*p[IW+1]  + w[5]*p[IW+2]
                + w[6]*p[2*IW]  + w[7]*p[2*IW+1]+ w[8]*p[2*IW+2];
        sum += v * g + bias;
    }
    __shared__ float red[256];
    red[threadIdx.x] = sum;
    __syncthreads();
    for (int s = 128; s > 0; s >>= 1) {
        if (threadIdx.x < s) red[threadIdx.x] += red[threadIdx.x + s];
        __syncthreads();
    }
    if (threadIdx.x == 0) meanbuf[b * RCn + rc] = red[0] / (float)FT;
}

// ---------------------------------------------------------------------------
// dyReLU coefficient MLP
// ---------------------------------------------------------------------------
__global__ void k_coef(const float* __restrict__ meanbuf, const float* __restrict__ w1,
                       const float* __restrict__ b1, const float* __restrict__ w2,
                       const float* __restrict__ b2, float* __restrict__ coef) {
    int b = blockIdx.x;
    int k = threadIdx.x;
    if (k >= 4 * RCn) return;
    const float* th = meanbuf + b * RCn;
    float h[6];
    #pragma unroll
    for (int j = 0; j < 6; j++) {
        float s = b1[j];
        #pragma unroll
        for (int c = 0; c < RCn; c++) s += th[c] * w1[j * RCn + c];
        h[j] = fmaxf(s, 0.f);
    }
    float s = b2[k];
    #pragma unroll
    for (int j = 0; j < 6; j++) s += h[j] * w2[k * 6 + j];
    float g2 = 2.f / (1.f + __expf(-s)) - 1.f;
    const float lam[4] = {1.f, 1.f, 0.5f, 0.5f};
    const float ini[4] = {1.f, 0.f, 0.f, 0.f};
    coef[b * 96 + k] = g2 * lam[k & 3] + ini[k & 3];
}

// ---------------------------------------------------------------------------
// recompute conv+BN, apply dyReLU, out += xr
// ---------------------------------------------------------------------------
__global__ void k_xr_add(const float* __restrict__ inp, const float* __restrict__ w_res,
                         const float* __restrict__ b_res, const float* __restrict__ bn_gamma,
                         const float* __restrict__ bn_beta, const float* __restrict__ bn_mean,
                         const float* __restrict__ bn_var, const float* __restrict__ coef,
                         float* __restrict__ out) {
    int gid = blockIdx.x * blockDim.x + threadIdx.x;
    if (gid >= Bn * RCn * FT) return;
    int t   = gid % Tn;
    int tmp = gid / Tn;
    int f   = tmp % Fn;  tmp /= Fn;
    int rc  = tmp % RCn;
    int b   = tmp / RCn;

    const float* wp = w_res + rc * 9;
    float g    = bn_gamma[rc] * rsqrtf(bn_var[rc] + 1e-5f);
    float bias = (b_res[rc] - bn_mean[rc]) * g + bn_beta[rc];
    const float* p = inp + (size_t)b * IH * IW + f * IW + t;
    float v = wp[0]*p[0]    + wp[1]*p[1]      + wp[2]*p[2]
            + wp[3]*p[IW]   + wp[4]*p[IW+1]   + wp[5]*p[IW+2]
            + wp[6]*p[2*IW] + wp[7]*p[2*IW+1] + wp[8]*p[2*IW+2];
    float xv = v * g + bias;

    const float* cf = coef + ((size_t)b * RCn + rc) * 4;
    float r = fmaxf(xv * cf[0] + cf[2], xv * cf[1] + cf[3]);
    out[gid] += r;
}

// ---------------------------------------------------------------------------
extern "C" void kernel_launch(void* const* d_in, const int* in_sizes, int n_in,
                              void* d_out, int out_size, void* d_ws, size_t ws_size,
                              hipStream_t stream) {
    const float* x        = (const float*)d_in[0];
    const float* inp      = (const float*)d_in[1];
    const float* w_diff   = (const float*)d_in[2];
    const float* b_diff   = (const float*)d_in[3];
    const float* w_res    = (const float*)d_in[4];
    const float* b_res    = (const float*)d_in[5];
    const float* bn_gamma = (const float*)d_in[6];
    const float* bn_beta  = (const float*)d_in[7];
    const float* bn_mean  = (const float*)d_in[8];
    const float* bn_var   = (const float*)d_in[9];
    const float* dy_w1    = (const float*)d_in[10];
    const float* dy_b1    = (const float*)d_in[11];
    const float* dy_w2    = (const float*)d_in[12];
    const float* dy_b2    = (const float*)d_in[13];
    const float* wq       = (const float*)d_in[14];
    const float* bq       = (const float*)d_in[15];
    const float* wk       = (const float*)d_in[16];
    const float* bk       = (const float*)d_in[17];
    const float* fq0_w    = (const float*)d_in[18];
    const float* fq0_b    = (const float*)d_in[19];
    const float* fk0_w    = (const float*)d_in[20];
    const float* fk0_b    = (const float*)d_in[21];
    const float* cq0_w    = (const float*)d_in[22];
    const float* cq0_b    = (const float*)d_in[23];
    const float* ck0_w    = (const float*)d_in[24];
    const float* ck0_b    = (const float*)d_in[25];
    const float* tq0_w    = (const float*)d_in[26];
    const float* tq0_b    = (const float*)d_in[27];
    const float* tk0_w    = (const float*)d_in[28];
    const float* tk0_b    = (const float*)d_in[29];
    const float* tq1_w    = (const float*)d_in[30];
    const float* tq1_b    = (const float*)d_in[31];
    const float* tk1_w    = (const float*)d_in[32];
    const float* tk1_b    = (const float*)d_in[33];

    float* out = (float*)d_out;
    float* ws  = (float*)d_ws;

    const size_t NB = (size_t)Bn * CFT;
    float* V       = ws;
    float* Q       = ws + NB;
    float* K       = ws + 2 * NB;
    float* Qp      = ws + 3 * NB;
    float* Kp      = ws + 4 * NB;
    float* S       = ws + 5 * NB;                       // Bn*Tn*Tn = 7.94M floats
    float* SP      = S + 4200000;                        // partials live in S-region tail
    float* meanbuf = S + (size_t)Bn * Tn * Tn;
    float* coef    = meanbuf + Bn * RCn;

    // 1. differ / Q / K
    {
        int total = Bn * FT;
        k_differ_qk<<<dim3((total + 255) / 256), dim3(256), 0, stream>>>(
            x, w_diff, b_diff, wq, bq, wk, bk, V, Q, K);
    }

    auto attend = [&](const float* Qv, const float* Kv, int n, int dq, int sQ,
                      int dv, int sec, int add, int KZ) {
        float scale = 1.0f / sqrtf((float)dq);
        int chunk = ((dq + KZ * 32 - 1) / (KZ * 32)) * 32;
        float* SPb = (KZ == 1) ? S : SP;
        dim3 g1((n + 63) / 64, (n + 63) / 64, Bn * KZ);
        k_scores_sk<<<g1, dim3(256), 0, stream>>>(Qv, Kv, SPb, n, dq, KZ, chunk, sQ);
        int nn = n * n;
        k_scombine<<<dim3((Bn * nn + 255) / 256), dim3(256), 0, stream>>>(SPb, S, n, KZ, scale);
        int mb = (n + 63) / 64;
        k_softmax<<<dim3(Bn * mb), dim3(64), 0, stream>>>(S, n, mb);
        dim3 g2((dv + 255) / 256, (n + 7) / 8, Bn);
        k_apply<<<g2, dim3(256), 0, stream>>>(S, V, out, n, dv, sec, add);
    };

    auto attend_c = [&](const float* Qv, const float* Kv, int add) {
        k_gram8<<<dim3(Bn * C_LZ), dim3(256), 0, stream>>>(Qv, Kv, SP);
        k_scombine<<<dim3((Bn * 64 + 255) / 256), dim3(256), 0, stream>>>(
            SP, S, Cn, C_LZ, 1.0f / sqrtf((float)FT));
        k_softmax<<<dim3(Bn), dim3(64), 0, stream>>>(S, Cn, 1);
        dim3 g2((FT + 255) / 256, 1, Bn);
        k_apply<<<g2, dim3(256), 0, stream>>>(S, V, out, Cn, FT, 1, add);
    };

    // ---- f branch: n=58, d=1992, sec=0, split-K 8
    attend(Q, K, Fn, 1992, CFT, 1992, 0, 0, 8);
    {
        dim3 g((1992 + 255) / 256, (Fn + 7) / 8, Bn);
        k_wmat<<<g, dim3(256), 0, stream>>>(Q, fq0_w, fq0_b, Qp, Fn, Fn, 1992, CFT, CFT);
        k_wmat<<<g, dim3(256), 0, stream>>>(K, fk0_w, fk0_b, Kp, Fn, Fn, 1992, CFT, CFT);
    }
    attend(Qp, Kp, Fn, 1992, CFT, 1992, 0, 1, 8);

    // ---- c branch: n=8, d=14442, sec=1 (specialized gram)
    attend_c(Q, K, 0);
    {
        dim3 g((FT + 255) / 256, 1, Bn);
        k_wmat<<<g, dim3(256), 0, stream>>>(Q, cq0_w, cq0_b, Qp, Cn, Cn, FT, CFT, CFT);
        k_wmat<<<g, dim3(256), 0, stream>>>(K, ck0_w, ck0_b, Kp, Cn, Cn, FT, CFT, CFT);
    }
    attend_c(Qp, Kp, 1);

    // ---- t branch: n=249, dv=464, sec=2
    attend(Q, K, Tn, 464, CFT, 464, 2, 0, 1);
    {
        dim3 g((464 + 255) / 256, (Tn + 7) / 8, Bn);
        k_wmat<<<g, dim3(256), 0, stream>>>(Q, tq0_w, tq0_b, Qp, Tn, Tn, 464, CFT, CFT);
        k_wmat<<<g, dim3(256), 0, stream>>>(K, tk0_w, tk0_b, Kp, Tn, Tn, 464, CFT, CFT);
    }
    attend(Qp, Kp, Tn, 464, CFT, 464, 2, 1, 1);
    {
        dim3 g(1, (Tn + 7) / 8, Bn);
        k_conv2s2<<<g, dim3(256), 0, stream>>>(Q, tq1_w, tq1_b, Qp, Tn, Tn, 464, 232, CFT, Tn * 232);
        k_conv2s2<<<g, dim3(256), 0, stream>>>(K, tk1_w, tk1_b, Kp, Tn, Tn, 464, 232, CFT, Tn * 232);
    }
    attend(Qp, Kp, Tn, 232, Tn * 232, 464, 2, 1, 1);

    // ---- xr residual path
    k_mean<<<dim3(Bn * RCn), dim3(256), 0, stream>>>(
        inp, w_res, b_res, bn_gamma, bn_beta, bn_mean, bn_var, meanbuf);
    k_coef<<<dim3(Bn), dim3(128), 0, stream>>>(meanbuf, dy_w1, dy_b1, dy_w2, dy_b2, coef);
    {
        int total = Bn * RCn * FT;
        k_xr_add<<<dim3((total + 255) / 256), dim3(256), 0, stream>>>(
            inp, w_res, b_res, bn_gamma, bn_beta, bn_mean, bn_var, coef, out);
    }
}

// Round 3
// 5483.361 us; speedup vs baseline: 1.9111x; 1.1294x over previous
//
#include <hip/hip_runtime.h>
#include <cmath>

#define Bn   128
#define Cn   8
#define Fn   58
#define Tn   249
#define RCn  24
#define FT   14442      // Fn*Tn
#define CFT  115536     // Cn*Fn*Tn
#define OUTB 346608     // 3*CFT per-batch output
#define IH   60
#define IW   251

// ---------------------------------------------------------------------------
// differ = concat([x[...,:1], W_diff@x + b_diff (shift) - x[...,:-1]], -1)
// Q = wq@differ + bq ; K = wk@differ + bk ; V = differ
// ---------------------------------------------------------------------------
__global__ void k_differ_qk(const float* __restrict__ x,
                            const float* __restrict__ w_diff, const float* __restrict__ b_diff,
                            const float* __restrict__ wq, const float* __restrict__ bq,
                            const float* __restrict__ wk, const float* __restrict__ bk,
                            float* __restrict__ V, float* __restrict__ Q, float* __restrict__ K) {
    int gid = blockIdx.x * blockDim.x + threadIdx.x;
    if (gid >= Bn * FT) return;
    int b  = gid / FT;
    int ft = gid % FT;
    int t  = ft % Tn;
    const float* xb = x + (size_t)b * CFT + ft;

    float xv[Cn], d[Cn];
    #pragma unroll
    for (int c = 0; c < Cn; c++) xv[c] = xb[c * FT];

    if (t == 0) {
        #pragma unroll
        for (int c = 0; c < Cn; c++) d[c] = xv[c];
    } else {
        #pragma unroll
        for (int o = 0; o < Cn; o++) {
            float s = b_diff[o];
            #pragma unroll
            for (int c = 0; c < Cn; c++) s += w_diff[o * Cn + c] * xv[c];
            d[o] = s - xb[o * FT - 1];
        }
    }

    float* Vb = V + (size_t)b * CFT + ft;
    float* Qb = Q + (size_t)b * CFT + ft;
    float* Kb = K + (size_t)b * CFT + ft;
    #pragma unroll
    for (int o = 0; o < Cn; o++) {
        Vb[o * FT] = d[o];
        float q = bq[o], k = bk[o];
        #pragma unroll
        for (int c = 0; c < Cn; c++) { q += wq[o * Cn + c] * d[c]; k += wk[o * Cn + c] * d[c]; }
        Qb[o * FT] = q;
        Kb[o * FT] = k;
    }
}

// ---------------------------------------------------------------------------
// Y[b,o,l] = sum_i W[o,i] X[b,i,l] + bias[o].
// LDS-staged W (transposed, pad-20 rows for aligned b128 broadcast reads),
// 16-row x VL-col register tile. (R2 lesson: per-thread uniform global loads
// of the small matrix are issue-bound; stage in LDS instead.)
// ---------------------------------------------------------------------------
template<int VL>
__global__ void __launch_bounds__(256)
k_wmat(const float* __restrict__ X, const float* __restrict__ W,
       const float* __restrict__ bias, float* __restrict__ Y,
       int n_out, int n_in, int d, int sX, int sY) {
    __shared__ float Ws[64][20];
    int tid = threadIdx.x;
    int l0  = blockIdx.x * (256 * VL) + tid;
    int og  = blockIdx.y * 16;
    int b   = blockIdx.z;
    const float* Xb = X + (size_t)b * sX;

    float acc[16][VL];
    #pragma unroll
    for (int j = 0; j < 16; j++) {
        float bv = bias[min(og + j, n_out - 1)];
        #pragma unroll
        for (int e = 0; e < VL; e++) acc[j][e] = bv;
    }

    for (int i0 = 0; i0 < n_in; i0 += 64) {
        int ic = min(64, n_in - i0);
        #pragma unroll
        for (int e = 0; e < 4; e++) {
            int idx = tid + e * 256;
            int r = idx >> 6, c = idx & 63;
            Ws[c][r] = (og + r < n_out && i0 + c < n_in)
                     ? W[(size_t)(og + r) * n_in + i0 + c] : 0.f;
        }
        __syncthreads();
        for (int ii = 0; ii < ic; ii++) {
            float4 a[4];
            a[0] = *(const float4*)&Ws[ii][0];
            a[1] = *(const float4*)&Ws[ii][4];
            a[2] = *(const float4*)&Ws[ii][8];
            a[3] = *(const float4*)&Ws[ii][12];
            #pragma unroll
            for (int e = 0; e < VL; e++) {
                int l = l0 + e * 256;
                if (l < d) {
                    float xv = Xb[(size_t)(i0 + ii) * d + l];
                    #pragma unroll
                    for (int j = 0; j < 4; j++) {
                        acc[4*j+0][e] += a[j].x * xv;
                        acc[4*j+1][e] += a[j].y * xv;
                        acc[4*j+2][e] += a[j].z * xv;
                        acc[4*j+3][e] += a[j].w * xv;
                    }
                }
            }
        }
        __syncthreads();
    }
    float* Yb = Y + (size_t)b * sY;
    #pragma unroll
    for (int j = 0; j < 16; j++) {
        if (og + j < n_out) {
            #pragma unroll
            for (int e = 0; e < VL; e++) {
                int l = l0 + e * 256;
                if (l < d) Yb[(size_t)(og + j) * d + l] = acc[j][e];
            }
        }
    }
}

// ---------------------------------------------------------------------------
// out[b,sec,og+j,l] (+)= sum_m A[b,og+j,m] V[b,m,l] — same structure as k_wmat
// ---------------------------------------------------------------------------
template<int VL>
__global__ void __launch_bounds__(256)
k_apply(const float* __restrict__ A, const float* __restrict__ V,
        float* __restrict__ out, int n, int dv, int sec, int add) {
    __shared__ float As[64][20];
    int tid = threadIdx.x;
    int l0  = blockIdx.x * (256 * VL) + tid;
    int ng  = blockIdx.y * 16;
    int b   = blockIdx.z;
    const float* Ab = A + (size_t)b * n * n;
    const float* Vb = V + (size_t)b * CFT;

    float acc[16][VL];
    #pragma unroll
    for (int j = 0; j < 16; j++)
        #pragma unroll
        for (int e = 0; e < VL; e++) acc[j][e] = 0.f;

    for (int m0 = 0; m0 < n; m0 += 64) {
        int mc = min(64, n - m0);
        #pragma unroll
        for (int e = 0; e < 4; e++) {
            int idx = tid + e * 256;
            int r = idx >> 6, c = idx & 63;
            As[c][r] = (ng + r < n && m0 + c < n)
                     ? Ab[(size_t)(ng + r) * n + m0 + c] : 0.f;
        }
        __syncthreads();
        for (int mm = 0; mm < mc; mm++) {
            float4 a[4];
            a[0] = *(const float4*)&As[mm][0];
            a[1] = *(const float4*)&As[mm][4];
            a[2] = *(const float4*)&As[mm][8];
            a[3] = *(const float4*)&As[mm][12];
            #pragma unroll
            for (int e = 0; e < VL; e++) {
                int l = l0 + e * 256;
                if (l < dv) {
                    float vv = Vb[(size_t)(m0 + mm) * dv + l];
                    #pragma unroll
                    for (int j = 0; j < 4; j++) {
                        acc[4*j+0][e] += a[j].x * vv;
                        acc[4*j+1][e] += a[j].y * vv;
                        acc[4*j+2][e] += a[j].z * vv;
                        acc[4*j+3][e] += a[j].w * vv;
                    }
                }
            }
        }
        __syncthreads();
    }
    float* ob = out + (size_t)b * OUTB + (size_t)sec * CFT;
    #pragma unroll
    for (int j = 0; j < 16; j++) {
        if (ng + j < n) {
            #pragma unroll
            for (int e = 0; e < VL; e++) {
                int l = l0 + e * 256;
                if (l < dv) {
                    size_t oi = (size_t)(ng + j) * dv + l;
                    ob[oi] = add ? (ob[oi] + acc[j][e]) : acc[j][e];
                }
            }
        }
    }
}

// ---------------------------------------------------------------------------
// kernel-2 stride-2 conv, LDS-staged weights. Block=128 threads, VL=2.
// ---------------------------------------------------------------------------
__global__ void __launch_bounds__(128)
k_conv2s2(const float* __restrict__ X, const float* __restrict__ W,
          const float* __restrict__ bias, float* __restrict__ Y,
          int n_out, int n_in, int d_in, int d_out, int sX, int sY) {
    __shared__ float W0s[64][20];
    __shared__ float W1s[64][20];
    int tid = threadIdx.x;
    int l0  = blockIdx.x * 256 + tid;
    int og  = blockIdx.y * 16;
    int b   = blockIdx.z;
    const float* Xb = X + (size_t)b * sX;

    float acc[16][2];
    #pragma unroll
    for (int j = 0; j < 16; j++) {
        float bv = bias[min(og + j, n_out - 1)];
        acc[j][0] = bv; acc[j][1] = bv;
    }

    for (int i0 = 0; i0 < n_in; i0 += 64) {
        int ic = min(64, n_in - i0);
        #pragma unroll
        for (int e = 0; e < 8; e++) {
            int idx = tid + e * 128;
            int r = idx >> 6, c = idx & 63;
            bool ok = (og + r < n_out) && (i0 + c < n_in);
            const float* wp = W + ((size_t)(og + r) * n_in + i0 + c) * 2;
            W0s[c][r] = ok ? wp[0] : 0.f;
            W1s[c][r] = ok ? wp[1] : 0.f;
        }
        __syncthreads();
        for (int ii = 0; ii < ic; ii++) {
            float4 a[4], bb[4];
            a[0]  = *(const float4*)&W0s[ii][0];
            a[1]  = *(const float4*)&W0s[ii][4];
            a[2]  = *(const float4*)&W0s[ii][8];
            a[3]  = *(const float4*)&W0s[ii][12];
            bb[0] = *(const float4*)&W1s[ii][0];
            bb[1] = *(const float4*)&W1s[ii][4];
            bb[2] = *(const float4*)&W1s[ii][8];
            bb[3] = *(const float4*)&W1s[ii][12];
            #pragma unroll
            for (int e = 0; e < 2; e++) {
                int l = l0 + e * 128;
                if (l < d_out) {
                    float2 xv = *(const float2*)&Xb[(size_t)(i0 + ii) * d_in + 2 * l];
                    #pragma unroll
                    for (int j = 0; j < 4; j++) {
                        acc[4*j+0][e] += a[j].x * xv.x + bb[j].x * xv.y;
                        acc[4*j+1][e] += a[j].y * xv.x + bb[j].y * xv.y;
                        acc[4*j+2][e] += a[j].z * xv.x + bb[j].z * xv.y;
                        acc[4*j+3][e] += a[j].w * xv.x + bb[j].w * xv.y;
                    }
                }
            }
        }
        __syncthreads();
    }
    float* Yb = Y + (size_t)b * sY;
    #pragma unroll
    for (int j = 0; j < 16; j++) {
        if (og + j < n_out) {
            #pragma unroll
            for (int e = 0; e < 2; e++) {
                int l = l0 + e * 128;
                if (l < d_out) Yb[(size_t)(og + j) * d_out + l] = acc[j][e];
            }
        }
    }
}

// ---------------------------------------------------------------------------
// Scores split-K: SP[bz,r,c] = sum_k Q[b,r,k]K[b,c,k]. 64x64 tile, 4x4/thread,
// float4 LDS fragment reads (rows 68 floats = 16B-aligned).
// ---------------------------------------------------------------------------
__global__ void __launch_bounds__(256)
k_scores_sk(const float* __restrict__ Q, const float* __restrict__ K,
            float* __restrict__ SP, int n, int d, int kz_n, int chunk, int sQ) {
    __shared__ float Qs[16][68];
    __shared__ float Ks[16][68];
    int bz = blockIdx.z;
    int b  = bz / kz_n, kz = bz % kz_n;
    int k0 = kz * chunk, k1 = min(d, k0 + chunk);
    int r0 = blockIdx.x * 64, c0 = blockIdx.y * 64;
    int tx = threadIdx.x & 15, ty = threadIdx.x >> 4;
    int lrow = threadIdx.x >> 2;
    int lk   = (threadIdx.x & 3) * 4;
    const float* Qr = Q + (size_t)b * sQ + (size_t)min(r0 + lrow, n - 1) * d;
    const float* Kr = K + (size_t)b * sQ + (size_t)min(c0 + lrow, n - 1) * d;
    bool qok = (r0 + lrow) < n;
    bool kok = (c0 + lrow) < n;
    float acc[4][4] = {};

    for (int kk = k0; kk < k1; kk += 16) {
        #pragma unroll
        for (int u = 0; u < 4; u++) {
            int gk = kk + lk + u;
            bool gv = gk < k1;
            Qs[lk + u][lrow] = (qok && gv) ? Qr[gk] : 0.f;
            Ks[lk + u][lrow] = (kok && gv) ? Kr[gk] : 0.f;
        }
        __syncthreads();
        #pragma unroll
        for (int k = 0; k < 16; k++) {
            float4 q4 = *(const float4*)&Qs[k][ty * 4];
            float4 k4 = *(const float4*)&Ks[k][tx * 4];
            float aq[4] = {q4.x, q4.y, q4.z, q4.w};
            float ak[4] = {k4.x, k4.y, k4.z, k4.w};
            #pragma unroll
            for (int i = 0; i < 4; i++)
                #pragma unroll
                for (int j = 0; j < 4; j++) acc[i][j] += aq[i] * ak[j];
        }
        __syncthreads();
    }
    float* Sb = SP + (size_t)bz * n * n;
    #pragma unroll
    for (int i = 0; i < 4; i++) {
        int r = r0 + ty * 4 + i;
        #pragma unroll
        for (int j = 0; j < 4; j++) {
            int c = c0 + tx * 4 + j;
            if (r < n && c < n) Sb[(size_t)r * n + c] = acc[i][j];
        }
    }
}

// ---------------------------------------------------------------------------
// Combine split-K partials (no scale — softmax folds 1/sqrt(d)).
// ---------------------------------------------------------------------------
__global__ void k_scombine(const float* __restrict__ SP, float* __restrict__ S,
                           int n, int kz_n) {
    int idx = blockIdx.x * 256 + threadIdx.x;
    int nn = n * n;
    if (idx >= Bn * nn) return;
    int b = idx / nn, rc = idx % nn;
    float s = 0.f;
    for (int kz = 0; kz < kz_n; kz++) s += SP[((size_t)b * kz_n + kz) * nn + rc];
    S[(size_t)b * nn + rc] = s;
}

// ---------------------------------------------------------------------------
// c-branch gram: 8x8 over d=FT, 8 l-chunks of partials.
// ---------------------------------------------------------------------------
#define C_LZ 8
__global__ void k_gram8(const float* __restrict__ Q, const float* __restrict__ K,
                        float* __restrict__ SP) {
    int b  = blockIdx.x / C_LZ;
    int lz = blockIdx.x % C_LZ;
    int g  = threadIdx.x >> 6;
    int p  = threadIdx.x & 63;
    int r  = p >> 3, c = p & 7;
    const float* Qb = Q + (size_t)b * CFT + (size_t)r * FT;
    const float* Kb = K + (size_t)b * CFT + (size_t)c * FT;
    int chunk = (FT + C_LZ - 1) / C_LZ;
    int l0 = lz * chunk, l1 = min(FT, l0 + chunk);
    float acc = 0.f;
    for (int l = l0 + g; l < l1; l += 4) acc += Qb[l] * Kb[l];
    __shared__ float red[256];
    red[threadIdx.x] = acc;
    __syncthreads();
    if (threadIdx.x < 64) {
        float s = red[p] + red[64 + p] + red[128 + p] + red[192 + p];
        SP[(size_t)blockIdx.x * 64 + p] = s;
    }
}

// ---------------------------------------------------------------------------
// column softmax in-place (axis=1), folds the 1/sqrt(d) scale.
// ---------------------------------------------------------------------------
__global__ void k_softmax(float* __restrict__ S, int n, int mb, float scale) {
    int b = blockIdx.x / mb;
    int m = (blockIdx.x % mb) * 64 + threadIdx.x;
    if (m >= n) return;
    float* Sb = S + (size_t)b * n * n;
    float mx = -1e30f;
    for (int r = 0; r < n; r++) mx = fmaxf(mx, Sb[(size_t)r * n + m]);
    float sum = 0.f;
    for (int r = 0; r < n; r++) {
        float e = __expf((Sb[(size_t)r * n + m] - mx) * scale);
        Sb[(size_t)r * n + m] = e;
        sum += e;
    }
    float inv = 1.f / sum;
    for (int r = 0; r < n; r++) Sb[(size_t)r * n + m] *= inv;
}

// ---------------------------------------------------------------------------
// xr spatial mean per (b, rc)
// ---------------------------------------------------------------------------
__global__ void k_mean(const float* __restrict__ inp, const float* __restrict__ w_res,
                       const float* __restrict__ b_res, const float* __restrict__ bn_gamma,
                       const float* __restrict__ bn_beta, const float* __restrict__ bn_mean,
                       const float* __restrict__ bn_var, float* __restrict__ meanbuf) {
    int b  = blockIdx.x / RCn;
    int rc = blockIdx.x % RCn;
    float w[9];
    #pragma unroll
    for (int i = 0; i < 9; i++) w[i] = w_res[rc * 9 + i];
    float g    = bn_gamma[rc] * rsqrtf(bn_var[rc] + 1e-5f);
    float bias = (b_res[rc] - bn_mean[rc]) * g + bn_beta[rc];
    const float* ib = inp + (size_t)b * IH * IW;

    float sum = 0.f;
    for (int idx = threadIdx.x; idx < FT; idx += 256) {
        int f = idx / Tn, t = idx % Tn;
        const float* p = ib + f * IW + t;
        float v = w[0]*p[0]     + w[1]*p[1]     + w[2]*p[2]
                + w[3]*p[IW]    + w[4]*p[IW+1]  + w[5]*p[IW+2]
                + w[6]*p[2*IW]  + w[7]*p[2*IW+1]+ w[8]*p[2*IW+2];
        sum += v * g + bias;
    }
    __shared__ float red[256];
    red[threadIdx.x] = sum;
    __syncthreads();
    for (int s = 128; s > 0; s >>= 1) {
        if (threadIdx.x < s) red[threadIdx.x] += red[threadIdx.x + s];
        __syncthreads();
    }
    if (threadIdx.x == 0) meanbuf[b * RCn + rc] = red[0] / (float)FT;
}

// ---------------------------------------------------------------------------
// dyReLU coefficient MLP
// ---------------------------------------------------------------------------
__global__ void k_coef(const float* __restrict__ meanbuf, const float* __restrict__ w1,
                       const float* __restrict__ b1, const float* __restrict__ w2,
                       const float* __restrict__ b2, float* __restrict__ coef) {
    int b = blockIdx.x;
    int k = threadIdx.x;
    if (k >= 4 * RCn) return;
    const float* th = meanbuf + b * RCn;
    float h[6];
    #pragma unroll
    for (int j = 0; j < 6; j++) {
        float s = b1[j];
        #pragma unroll
        for (int c = 0; c < RCn; c++) s += th[c] * w1[j * RCn + c];
        h[j] = fmaxf(s, 0.f);
    }
    float s = b2[k];
    #pragma unroll
    for (int j = 0; j < 6; j++) s += h[j] * w2[k * 6 + j];
    float g2 = 2.f / (1.f + __expf(-s)) - 1.f;
    const float lam[4] = {1.f, 1.f, 0.5f, 0.5f};
    const float ini[4] = {1.f, 0.f, 0.f, 0.f};
    coef[b * 96 + k] = g2 * lam[k & 3] + ini[k & 3];
}

// ---------------------------------------------------------------------------
// recompute conv+BN, apply dyReLU, out += xr
// ---------------------------------------------------------------------------
__global__ void k_xr_add(const float* __restrict__ inp, const float* __restrict__ w_res,
                         const float* __restrict__ b_res, const float* __restrict__ bn_gamma,
                         const float* __restrict__ bn_beta, const float* __restrict__ bn_mean,
                         const float* __restrict__ bn_var, const float* __restrict__ coef,
                         float* __restrict__ out) {
    int gid = blockIdx.x * blockDim.x + threadIdx.x;
    if (gid >= Bn * RCn * FT) return;
    int t   = gid % Tn;
    int tmp = gid / Tn;
    int f   = tmp % Fn;  tmp /= Fn;
    int rc  = tmp % RCn;
    int b   = tmp / RCn;

    const float* wp = w_res + rc * 9;
    float g    = bn_gamma[rc] * rsqrtf(bn_var[rc] + 1e-5f);
    float bias = (b_res[rc] - bn_mean[rc]) * g + bn_beta[rc];
    const float* p = inp + (size_t)b * IH * IW + f * IW + t;
    float v = wp[0]*p[0]    + wp[1]*p[1]      + wp[2]*p[2]
            + wp[3]*p[IW]   + wp[4]*p[IW+1]   + wp[5]*p[IW+2]
            + wp[6]*p[2*IW] + wp[7]*p[2*IW+1] + wp[8]*p[2*IW+2];
    float xv = v * g + bias;

    const float* cf = coef + ((size_t)b * RCn + rc) * 4;
    float r = fmaxf(xv * cf[0] + cf[2], xv * cf[1] + cf[3]);
    out[gid] += r;
}

// ---------------------------------------------------------------------------
extern "C" void kernel_launch(void* const* d_in, const int* in_sizes, int n_in,
                              void* d_out, int out_size, void* d_ws, size_t ws_size,
                              hipStream_t stream) {
    const float* x        = (const float*)d_in[0];
    const float* inp      = (const float*)d_in[1];
    const float* w_diff   = (const float*)d_in[2];
    const float* b_diff   = (const float*)d_in[3];
    const float* w_res    = (const float*)d_in[4];
    const float* b_res    = (const float*)d_in[5];
    const float* bn_gamma = (const float*)d_in[6];
    const float* bn_beta  = (const float*)d_in[7];
    const float* bn_mean  = (const float*)d_in[8];
    const float* bn_var   = (const float*)d_in[9];
    const float* dy_w1    = (const float*)d_in[10];
    const float* dy_b1    = (const float*)d_in[11];
    const float* dy_w2    = (const float*)d_in[12];
    const float* dy_b2    = (const float*)d_in[13];
    const float* wq       = (const float*)d_in[14];
    const float* bq       = (const float*)d_in[15];
    const float* wk       = (const float*)d_in[16];
    const float* bk       = (const float*)d_in[17];
    const float* fq0_w    = (const float*)d_in[18];
    const float* fq0_b    = (const float*)d_in[19];
    const float* fk0_w    = (const float*)d_in[20];
    const float* fk0_b    = (const float*)d_in[21];
    const float* cq0_w    = (const float*)d_in[22];
    const float* cq0_b    = (const float*)d_in[23];
    const float* ck0_w    = (const float*)d_in[24];
    const float* ck0_b    = (const float*)d_in[25];
    const float* tq0_w    = (const float*)d_in[26];
    const float* tq0_b    = (const float*)d_in[27];
    const float* tk0_w    = (const float*)d_in[28];
    const float* tk0_b    = (const float*)d_in[29];
    const float* tq1_w    = (const float*)d_in[30];
    const float* tq1_b    = (const float*)d_in[31];
    const float* tk1_w    = (const float*)d_in[32];
    const float* tk1_b    = (const float*)d_in[33];

    float* out = (float*)d_out;
    float* ws  = (float*)d_ws;

    const size_t NB = (size_t)Bn * CFT;
    float* V       = ws;
    float* Q       = ws + NB;
    float* K       = ws + 2 * NB;
    float* Qp      = ws + 3 * NB;
    float* Kp      = ws + 4 * NB;
    float* S       = ws + 5 * NB;                       // up to Bn*Tn*Tn floats
    float* SP      = S + 4200000;                        // split-K partials
    float* meanbuf = S + (size_t)Bn * Tn * Tn;
    float* coef    = meanbuf + Bn * RCn;

    {
        int total = Bn * FT;
        k_differ_qk<<<dim3((total + 255) / 256), dim3(256), 0, stream>>>(
            x, w_diff, b_diff, wq, bq, wk, bk, V, Q, K);
    }

    auto wmat = [&](const float* X, const float* W, const float* bias, float* Y,
                    int n_out, int n_in, int d) {
        dim3 gy((n_out + 15) / 16);
        if (d > 1000) {
            dim3 g((d + 1023) / 1024, gy.x, Bn);
            k_wmat<4><<<g, dim3(256), 0, stream>>>(X, W, bias, Y, n_out, n_in, d, CFT, CFT);
        } else {
            dim3 g((d + 511) / 512, gy.x, Bn);
            k_wmat<2><<<g, dim3(256), 0, stream>>>(X, W, bias, Y, n_out, n_in, d, CFT, CFT);
        }
    };

    auto attend = [&](const float* Qv, const float* Kv, int n, int dq, int sQ,
                      int dv, int sec, int add, int KZ) {
        float scale = 1.0f / sqrtf((float)dq);
        int chunk = ((dq + KZ * 32 - 1) / (KZ * 32)) * 32;
        float* SPb = (KZ == 1) ? S : SP;
        dim3 g1((n + 63) / 64, (n + 63) / 64, Bn * KZ);
        k_scores_sk<<<g1, dim3(256), 0, stream>>>(Qv, Kv, SPb, n, dq, KZ, chunk, sQ);
        if (KZ > 1) {
            int nn = n * n;
            k_scombine<<<dim3((Bn * nn + 255) / 256), dim3(256), 0, stream>>>(SPb, S, n, KZ);
        }
        int mb = (n + 63) / 64;
        k_softmax<<<dim3(Bn * mb), dim3(64), 0, stream>>>(S, n, mb, scale);
        dim3 gy((n + 15) / 16);
        if (dv > 1000) {
            dim3 g2((dv + 1023) / 1024, gy.x, Bn);
            k_apply<4><<<g2, dim3(256), 0, stream>>>(S, V, out, n, dv, sec, add);
        } else {
            dim3 g2((dv + 511) / 512, gy.x, Bn);
            k_apply<2><<<g2, dim3(256), 0, stream>>>(S, V, out, n, dv, sec, add);
        }
    };

    auto attend_c = [&](const float* Qv, const float* Kv, int add) {
        k_gram8<<<dim3(Bn * C_LZ), dim3(256), 0, stream>>>(Qv, Kv, SP);
        k_scombine<<<dim3((Bn * 64 + 255) / 256), dim3(256), 0, stream>>>(SP, S, Cn, C_LZ);
        k_softmax<<<dim3(Bn), dim3(64), 0, stream>>>(S, Cn, 1, 1.0f / sqrtf((float)FT));
        dim3 g2((FT + 1023) / 1024, 1, Bn);
        k_apply<4><<<g2, dim3(256), 0, stream>>>(S, V, out, Cn, FT, 1, add);
    };

    // ---- f branch: n=58, d=1992, sec=0, split-K 8
    attend(Q, K, Fn, 1992, CFT, 1992, 0, 0, 8);
    wmat(Q, fq0_w, fq0_b, Qp, Fn, Fn, 1992);
    wmat(K, fk0_w, fk0_b, Kp, Fn, Fn, 1992);
    attend(Qp, Kp, Fn, 1992, CFT, 1992, 0, 1, 8);

    // ---- c branch: n=8, d=14442, sec=1
    attend_c(Q, K, 0);
    wmat(Q, cq0_w, cq0_b, Qp, Cn, Cn, FT);
    wmat(K, ck0_w, ck0_b, Kp, Cn, Cn, FT);
    attend_c(Qp, Kp, 1);

    // ---- t branch: n=249, dv=464, sec=2
    attend(Q, K, Tn, 464, CFT, 464, 2, 0, 1);
    wmat(Q, tq0_w, tq0_b, Qp, Tn, Tn, 464);
    wmat(K, tk0_w, tk0_b, Kp, Tn, Tn, 464);
    attend(Qp, Kp, Tn, 464, CFT, 464, 2, 1, 1);
    {
        dim3 g(1, (Tn + 15) / 16, Bn);
        k_conv2s2<<<g, dim3(128), 0, stream>>>(Q, tq1_w, tq1_b, Qp, Tn, Tn, 464, 232, CFT, Tn * 232);
        k_conv2s2<<<g, dim3(128), 0, stream>>>(K, tk1_w, tk1_b, Kp, Tn, Tn, 464, 232, CFT, Tn * 232);
    }
    attend(Qp, Kp, Tn, 232, Tn * 232, 464, 2, 1, 1);

    // ---- xr residual path
    k_mean<<<dim3(Bn * RCn), dim3(256), 0, stream>>>(
        inp, w_res, b_res, bn_gamma, bn_beta, bn_mean, bn_var, meanbuf);
    k_coef<<<dim3(Bn), dim3(128), 0, stream>>>(meanbuf, dy_w1, dy_b1, dy_w2, dy_b2, coef);
    {
        int total = Bn * RCn * FT;
        k_xr_add<<<dim3((total + 255) / 256), dim3(256), 0, stream>>>(
            inp, w_res, b_res, bn_gamma, bn_beta, bn_mean, bn_var, coef, out);
    }
}